// Round 5
// baseline (1022.876 us; speedup 1.0000x reference)
//
#include <hip/hip_runtime.h>

// ---------------------------------------------------------------------------
// GNN: 3x GraphConv (norm='both') + avg-pool + MLP(128->512->256->1), fp32.
// R5: fuse csr_agg + per-layer GEMM. Each block gathers its 64-node A-tile
// (CSR gather, inv_dst applied) straight into LDS, then does the 128x128
// GEMM from LDS. Saves agg write + A read (~100 MB/layer) + 1 launch/layer.
// CSR build: atomic-free counting sort (R4). MLP head keeps plain gemm.
// ---------------------------------------------------------------------------

static inline int ceil_div(int a, int b){ return (a + b - 1) / b; }

#define B1 128          // pass-1 blocks
#define NBMAX 1024      // max buckets (N <= 131072)

// Pass 1a: per-block bucket counts for dst (job A) and src (job B).
__global__ __launch_bounds__(256) void bucket_count_kernel(
    const int* __restrict__ src, const int* __restrict__ dst,
    unsigned* __restrict__ cntA, unsigned* __restrict__ cntB,
    int E, int NB){
  __shared__ unsigned la[NBMAX], lb[NBMAX];
  int t = threadIdx.x;
  for (int i = t; i < NB; i += 256){ la[i] = 0u; lb[i] = 0u; }
  __syncthreads();
  int chunk = (E + B1 - 1) / B1;
  int e0 = blockIdx.x * chunk, e1 = min(e0 + chunk, E);
  for (int e = e0 + t; e < e1; e += 256){
    atomicAdd(&la[dst[e] >> 7], 1u);
    atomicAdd(&lb[src[e] >> 7], 1u);
  }
  __syncthreads();
  for (int i = t; i < NB; i += 256){
    cntA[(size_t)blockIdx.x * NB + i] = la[i];
    cntB[(size_t)blockIdx.x * NB + i] = lb[i];
  }
}

// Column-wise exclusive scan over blocks for each bucket; emits totals.
__global__ void scan_cols_kernel(unsigned* __restrict__ cntA, unsigned* __restrict__ cntB,
                                 unsigned* __restrict__ totals, int NB){
  int b = blockIdx.x * 256 + threadIdx.x;
  if (b >= NB) return;
  unsigned* cnt = blockIdx.y ? cntB : cntA;
  unsigned run = 0;
  for (int blk = 0; blk < B1; blk++){
    unsigned v = cnt[(size_t)blk * NB + b];
    cnt[(size_t)blk * NB + b] = run;
    run += v;
  }
  totals[(size_t)blockIdx.y * NB + b] = run;
}

// Single-block exclusive scan of bucket totals -> baseA/baseB (each NB+1).
__global__ void scan_base_kernel(const unsigned* __restrict__ totals,
                                 unsigned* __restrict__ baseA, unsigned* __restrict__ baseB,
                                 int NB, int E){
  __shared__ unsigned s[NBMAX];
  int t = threadIdx.x;  // 1024 threads, NB <= 1024
  for (int job = 0; job < 2; job++){
    unsigned* base = job ? baseB : baseA;
    unsigned x = (t < NB) ? totals[(size_t)job * NB + t] : 0u;
    s[t] = x;
    __syncthreads();
    for (int off = 1; off < NBMAX; off <<= 1){
      unsigned v = (t >= off) ? s[t - off] : 0u;
      __syncthreads();
      s[t] += v;
      __syncthreads();
    }
    if (t < NB) base[t] = s[t] - x;
    if (t == 0) base[NB] = (unsigned)E;
    __syncthreads();
  }
}

// Pass 1b: scatter edges into bucketed arrays using per-block reserved offsets.
__global__ __launch_bounds__(256) void bucket_scatter_kernel(
    const int* __restrict__ src, const int* __restrict__ dst,
    const unsigned* __restrict__ cntA, const unsigned* __restrict__ cntB,
    const unsigned* __restrict__ baseA, const unsigned* __restrict__ baseB,
    int* __restrict__ bsrc_d, int* __restrict__ bdst_d, int* __restrict__ bsrc_s,
    int E, int NB){
  __shared__ unsigned curA[NBMAX], curB[NBMAX];
  int t = threadIdx.x;
  for (int i = t; i < NB; i += 256){
    curA[i] = baseA[i] + cntA[(size_t)blockIdx.x * NB + i];
    curB[i] = baseB[i] + cntB[(size_t)blockIdx.x * NB + i];
  }
  __syncthreads();
  int chunk = (E + B1 - 1) / B1;
  int e0 = blockIdx.x * chunk, e1 = min(e0 + chunk, E);
  for (int e = e0 + t; e < e1; e += 256){
    int s = src[e], d = dst[e];
    unsigned p = atomicAdd(&curA[d >> 7], 1u);
    bsrc_d[p] = s;
    bdst_d[p] = d;
    unsigned q = atomicAdd(&curB[s >> 7], 1u);
    bsrc_s[q] = s;
  }
}

// Pass 2a: per-bucket CSR finalize: row_ptr, inv_dst, col (contiguous range).
__global__ __launch_bounds__(256) void csr_finalize_kernel(
    const int* __restrict__ bsrc_d, const int* __restrict__ bdst_d,
    const unsigned* __restrict__ baseA,
    int* __restrict__ row_ptr, float* __restrict__ inv_dst, int* __restrict__ col,
    int N, int E, int NB){
  __shared__ unsigned cnt[128];
  __shared__ unsigned scn[128];
  int b = blockIdx.x, t = threadIdx.x;
  int node0 = b << 7;
  int nn = min(128, N - node0);
  int e0 = (int)baseA[b], e1 = (int)baseA[b + 1];
  if (t < 128) cnt[t] = 0u;
  __syncthreads();
  for (int e = e0 + t; e < e1; e += 256)
    atomicAdd(&cnt[bdst_d[e] & 127], 1u);
  __syncthreads();
  unsigned mycnt = (t < 128) ? cnt[t] : 0u;
  if (t < 128) scn[t] = mycnt;
  __syncthreads();
  for (int off = 1; off < 128; off <<= 1){
    unsigned v = (t < 128 && t >= off) ? scn[t - off] : 0u;
    __syncthreads();
    if (t < 128) scn[t] += v;
    __syncthreads();
  }
  if (t < nn){
    unsigned excl = scn[t] - mycnt;
    row_ptr[node0 + t] = e0 + (int)excl;
    unsigned c = mycnt < 1u ? 1u : mycnt;
    inv_dst[node0 + t] = rsqrtf((float)c);
    cnt[t] = (unsigned)e0 + excl;   // reuse as cursor
  }
  if (b == NB - 1 && t == 0) row_ptr[N] = E;
  __syncthreads();
  for (int e = e0 + t; e < e1; e += 256){
    unsigned p = atomicAdd(&cnt[bdst_d[e] & 127], 1u);
    col[p] = bsrc_d[e];
  }
}

// Pass 2b: per-bucket out-degree -> inv_src.
__global__ __launch_bounds__(256) void degout_finalize_kernel(
    const int* __restrict__ bsrc_s, const unsigned* __restrict__ baseB,
    float* __restrict__ inv_src, int N){
  __shared__ unsigned cnt[128];
  int b = blockIdx.x, t = threadIdx.x;
  int node0 = b << 7;
  int nn = min(128, N - node0);
  int e0 = (int)baseB[b], e1 = (int)baseB[b + 1];
  if (t < 128) cnt[t] = 0u;
  __syncthreads();
  for (int e = e0 + t; e < e1; e += 256)
    atomicAdd(&cnt[bsrc_s[e] & 127], 1u);
  __syncthreads();
  if (t < nn){
    unsigned c = cnt[t] < 1u ? 1u : cnt[t];
    inv_src[node0 + t] = rsqrtf((float)c);
  }
}

// hs = feats * inv_src (row scale), float4 vectorized
__global__ void scale_rows_kernel(const float* __restrict__ in, const float* __restrict__ sc,
                                  float* __restrict__ out, int n4){
  int i = blockIdx.x*blockDim.x + threadIdx.x;
  if (i < n4){
    float4 v = ((const float4*)in)[i];
    float s = sc[i >> 5];            // 32 float4 per 128-wide row
    v.x *= s; v.y *= s; v.z *= s; v.w *= s;
    ((float4*)out)[i] = v;
  }
}

// ---------------------------------------------------------------------------
// Fused GraphConv layer: per block of 64 nodes,
//   phase 1 (4 waves): CSR-gather each node's agg row (x inv_dst) into LDS As
//   phase 2: 64x128x128 GEMM from LDS, epilogue relu(+bias)(*out_scale).
// out[m] = relu( (inv_dst[m] * sum_{e in-edges} hs[col[e]]) @ Wt + bias ) * out_scale[m]
// ---------------------------------------------------------------------------
__global__ __launch_bounds__(256) void agg_gemm_kernel(
    const int* __restrict__ row_ptr, const int* __restrict__ col,
    const float* __restrict__ hs, const float* __restrict__ Wt,
    const float* __restrict__ bias, const float* __restrict__ inv_dst,
    const float* __restrict__ out_scale, float* __restrict__ out, int N){
  __shared__ float As[128][68];    // [k][m]
  __shared__ float Bs[32][128];    // [k][j]

  const int tid = threadIdx.x;
  const int wave = tid >> 6;
  const int lane = tid & 63;
  const int row0 = blockIdx.x * 64;

  // ---- phase 1: gather A tile into LDS ----
  for (int mi = wave; mi < 64; mi += 4){
    int node = row0 + mi;
    float rx = 0.f, ry = 0.f;
    if (node < N){
      int r0 = __builtin_amdgcn_readfirstlane(row_ptr[node]);
      int r1 = __builtin_amdgcn_readfirstlane(row_ptr[node+1]);
      float ax0=0.f, ay0=0.f, ax1=0.f, ay1=0.f;
      float ax2=0.f, ay2=0.f, ax3=0.f, ay3=0.f;
      int e = r0;
      for (; e + 3 < r1; e += 4){
        int s0 = __builtin_amdgcn_readfirstlane(col[e]);
        int s1 = __builtin_amdgcn_readfirstlane(col[e+1]);
        int s2 = __builtin_amdgcn_readfirstlane(col[e+2]);
        int s3 = __builtin_amdgcn_readfirstlane(col[e+3]);
        float2 v0 = ((const float2*)(hs + (size_t)s0*128))[lane];
        float2 v1 = ((const float2*)(hs + (size_t)s1*128))[lane];
        float2 v2 = ((const float2*)(hs + (size_t)s2*128))[lane];
        float2 v3 = ((const float2*)(hs + (size_t)s3*128))[lane];
        ax0 += v0.x; ay0 += v0.y;
        ax1 += v1.x; ay1 += v1.y;
        ax2 += v2.x; ay2 += v2.y;
        ax3 += v3.x; ay3 += v3.y;
      }
      for (; e < r1; e++){
        int s0 = __builtin_amdgcn_readfirstlane(col[e]);
        float2 v0 = ((const float2*)(hs + (size_t)s0*128))[lane];
        ax0 += v0.x; ay0 += v0.y;
      }
      float idst = inv_dst[node];
      rx = ((ax0 + ax1) + (ax2 + ax3)) * idst;
      ry = ((ay0 + ay1) + (ay2 + ay3)) * idst;
    }
    As[2*lane][mi]   = rx;
    As[2*lane+1][mi] = ry;
  }
  __syncthreads();

  // ---- phase 2: GEMM from LDS ----
  const int tx = tid & 31;
  const int ty = tid >> 5;
  float acc[8][4];
  #pragma unroll
  for (int i = 0; i < 8; i++)
    #pragma unroll
    for (int j = 0; j < 4; j++) acc[i][j] = 0.f;

  for (int kb = 0; kb < 128; kb += 32){
    #pragma unroll
    for (int i = 0; i < 4; i++){
      int flat = i*256 + tid;
      int k = flat >> 5, j4 = (flat & 31) << 2;
      *(float4*)&Bs[k][j4] = *(const float4*)(Wt + (size_t)(kb + k)*128 + j4);
    }
    __syncthreads();
    #pragma unroll
    for (int k = 0; k < 32; k++){
      float4 b = *(const float4*)&Bs[k][tx << 2];
      float a[8];
      #pragma unroll
      for (int i = 0; i < 8; i++) a[i] = As[kb + k][ty*8 + i];
      #pragma unroll
      for (int i = 0; i < 8; i++){
        acc[i][0] = fmaf(a[i], b.x, acc[i][0]);
        acc[i][1] = fmaf(a[i], b.y, acc[i][1]);
        acc[i][2] = fmaf(a[i], b.z, acc[i][2]);
        acc[i][3] = fmaf(a[i], b.w, acc[i][3]);
      }
    }
    __syncthreads();
  }

  float4 bi = *(const float4*)(bias + (tx << 2));
  #pragma unroll
  for (int i = 0; i < 8; i++){
    int gm = row0 + ty*8 + i;
    if (gm < N){
      float4 v;
      v.x = fmaxf(acc[i][0] + bi.x, 0.f);
      v.y = fmaxf(acc[i][1] + bi.y, 0.f);
      v.z = fmaxf(acc[i][2] + bi.z, 0.f);
      v.w = fmaxf(acc[i][3] + bi.w, 0.f);
      if (out_scale){ float s = out_scale[gm]; v.x*=s; v.y*=s; v.z*=s; v.w*=s; }
      *(float4*)(out + (size_t)gm*128 + (tx << 2)) = v;
    }
  }
}

// Tiled fp32 SGEMM for the MLP head (unchanged).
__global__ __launch_bounds__(256) void gemm_kernel(
    const float* __restrict__ A, const float* __restrict__ W,
    const float* __restrict__ bias, const float* __restrict__ row_scale,
    const float* __restrict__ out_scale, float* __restrict__ out,
    int M, int K, int Ncols, int do_relu){
  __shared__ float As[32][68];
  __shared__ float Bs[32][128];

  const int tid = threadIdx.x;
  const int tx = tid & 31;
  const int ty = tid >> 5;
  const int row0 = blockIdx.x * 64;
  const int col0 = blockIdx.y * 128;

  float acc[8][4];
  #pragma unroll
  for (int i = 0; i < 8; i++)
    #pragma unroll
    for (int j = 0; j < 4; j++) acc[i][j] = 0.f;

  for (int kb = 0; kb < K; kb += 32){
    #pragma unroll
    for (int i = 0; i < 2; i++){
      int flat = i*256 + tid;
      int m = flat >> 3, k4 = (flat & 7) << 2;
      int gm = row0 + m;
      float4 v = make_float4(0.f, 0.f, 0.f, 0.f);
      if (gm < M){
        v = *(const float4*)(A + (size_t)gm*K + kb + k4);
        if (row_scale){ float s = row_scale[gm]; v.x*=s; v.y*=s; v.z*=s; v.w*=s; }
      }
      As[k4+0][m] = v.x; As[k4+1][m] = v.y; As[k4+2][m] = v.z; As[k4+3][m] = v.w;
    }
    #pragma unroll
    for (int i = 0; i < 4; i++){
      int flat = i*256 + tid;
      int k = flat >> 5, j4 = (flat & 31) << 2;
      float4 v = *(const float4*)(W + (size_t)(kb + k)*Ncols + col0 + j4);
      *(float4*)&Bs[k][j4] = v;
    }
    __syncthreads();
    #pragma unroll
    for (int k = 0; k < 32; k++){
      float4 b = *(const float4*)&Bs[k][tx << 2];
      float a[8];
      #pragma unroll
      for (int i = 0; i < 8; i++) a[i] = As[k][ty*8 + i];
      #pragma unroll
      for (int i = 0; i < 8; i++){
        acc[i][0] = fmaf(a[i], b.x, acc[i][0]);
        acc[i][1] = fmaf(a[i], b.y, acc[i][1]);
        acc[i][2] = fmaf(a[i], b.z, acc[i][2]);
        acc[i][3] = fmaf(a[i], b.w, acc[i][3]);
      }
    }
    __syncthreads();
  }

  float4 bi = *(const float4*)(bias + col0 + (tx << 2));
  #pragma unroll
  for (int i = 0; i < 8; i++){
    int gm = row0 + ty*8 + i;
    if (gm < M){
      float4 v;
      v.x = acc[i][0] + bi.x; v.y = acc[i][1] + bi.y;
      v.z = acc[i][2] + bi.z; v.w = acc[i][3] + bi.w;
      if (do_relu){
        v.x = fmaxf(v.x, 0.f); v.y = fmaxf(v.y, 0.f);
        v.z = fmaxf(v.z, 0.f); v.w = fmaxf(v.w, 0.f);
      }
      if (out_scale){ float s = out_scale[gm]; v.x*=s; v.y*=s; v.z*=s; v.w*=s; }
      *(float4*)(out + (size_t)gm*Ncols + col0 + (tx << 2)) = v;
    }
  }
}

// Avg-pool per graph: graph_ids sorted -> binary search bounds, wave per graph.
__global__ void pool_kernel(const float* __restrict__ h, const int* __restrict__ gid,
                            float* __restrict__ emb, int N, int G){
  int g = blockIdx.x;
  int lane = threadIdx.x;   // 64 threads
  int lo = 0, hi = N;
  while (lo < hi){ int mid = (lo + hi) >> 1; if (gid[mid] < g) lo = mid + 1; else hi = mid; }
  int start = lo;
  hi = N;
  while (lo < hi){ int mid = (lo + hi) >> 1; if (gid[mid] <= g) lo = mid + 1; else hi = mid; }
  int end = lo;
  float ax = 0.f, ay = 0.f;
  for (int n = start; n < end; n++){
    float2 v = ((const float2*)(h + (size_t)n*128))[lane];
    ax += v.x; ay += v.y;
  }
  int c = end - start; if (c < 1) c = 1;
  float invc = 1.0f / (float)c;
  float2 r; r.x = ax * invc; r.y = ay * invc;
  ((float2*)(emb + (size_t)g*128))[lane] = r;
}

// Final 256->1: wave per graph, float4 per lane, shuffle reduce.
__global__ void final_dot_kernel(const float* __restrict__ x, const float* __restrict__ w,
                                 const float* __restrict__ b, float* __restrict__ out, int G){
  int idx = blockIdx.x*blockDim.x + threadIdx.x;
  int g = idx >> 6, lane = idx & 63;
  if (g >= G) return;
  float4 xv = ((const float4*)(x + (size_t)g*256))[lane];
  float4 wv = ((const float4*)w)[lane];
  float s = xv.x*wv.x + xv.y*wv.y + xv.z*wv.z + xv.w*wv.w;
  for (int off = 32; off > 0; off >>= 1) s += __shfl_down(s, off);
  if (lane == 0) out[g] = s + b[0];
}

extern "C" void kernel_launch(void* const* d_in, const int* in_sizes, int n_in,
                              void* d_out, int out_size, void* d_ws, size_t ws_size,
                              hipStream_t stream){
  const float* feats = (const float*)d_in[0];
  const int*   src   = (const int*)d_in[1];
  const int*   dst   = (const int*)d_in[2];
  const int*   gid   = (const int*)d_in[3];
  const float* W0 = (const float*)d_in[4];   const float* b0 = (const float*)d_in[5];
  const float* W1 = (const float*)d_in[6];   const float* b1 = (const float*)d_in[7];
  const float* W2 = (const float*)d_in[8];   const float* b2 = (const float*)d_in[9];
  const float* Wm0 = (const float*)d_in[10]; const float* bm0 = (const float*)d_in[11];
  const float* Wm1 = (const float*)d_in[12]; const float* bm1 = (const float*)d_in[13];
  const float* Wm2 = (const float*)d_in[14]; const float* bm2 = (const float*)d_in[15];
  float* out = (float*)d_out;

  const int E   = in_sizes[1];
  const int N   = in_sizes[3];
  const int G   = out_size;
  const int MH  = in_sizes[11];   // 512
  const int MH2 = in_sizes[13];   // 256
  const int NB  = ceil_div(N, 128);   // 782 for N=100000 (<= NBMAX)

  char* ws = (char*)d_ws;
  size_t off = 0;
  auto carve = [&](size_t bytes) -> char* {
    off = (off + 255) & ~(size_t)255;
    char* p = ws + off; off += bytes; return p;
  };
  float* inv_src = (float*)carve((size_t)N*4);
  float* inv_dst = (float*)carve((size_t)N*4);
  int* row_ptr = (int*)carve((size_t)(N+1)*4);
  int* col     = (int*)carve((size_t)E*4);
  float* hs  = (float*)carve((size_t)N*128*4);
  float* h2  = (float*)carve((size_t)N*128*4);
  float* emb = (float*)carve((size_t)G*128*4);
  float* x1  = (float*)carve((size_t)G*MH*4);
  float* x2  = (float*)carve((size_t)G*MH2*4);

  // CSR-build temporaries alias h2 (dead until first agg_gemm writes it).
  // u32 layout: cntA[B1*NB] | cntB[B1*NB] | totals[2*NB] | baseA[NB+1] | baseB[NB+1]
  //             | bsrc_d[E] | bdst_d[E] | bsrc_s[E]
  unsigned* T = (unsigned*)h2;
  unsigned* cntA   = T;
  unsigned* cntB   = cntA + (size_t)B1*NB;
  unsigned* totals = cntB + (size_t)B1*NB;
  unsigned* baseA  = totals + 2*(size_t)NB;
  unsigned* baseB  = baseA + (NB+1);
  int* bsrc_d = (int*)(baseB + (NB+1));
  int* bdst_d = bsrc_d + E;
  int* bsrc_s = bdst_d + E;

  bucket_count_kernel<<<B1, 256, 0, stream>>>(src, dst, cntA, cntB, E, NB);
  scan_cols_kernel<<<dim3(ceil_div(NB,256), 2), 256, 0, stream>>>(cntA, cntB, totals, NB);
  scan_base_kernel<<<1, NBMAX, 0, stream>>>(totals, baseA, baseB, NB, E);
  bucket_scatter_kernel<<<B1, 256, 0, stream>>>(src, dst, cntA, cntB, baseA, baseB,
                                                bsrc_d, bdst_d, bsrc_s, E, NB);
  csr_finalize_kernel<<<NB, 256, 0, stream>>>(bsrc_d, bdst_d, baseA, row_ptr, inv_dst, col, N, E, NB);
  degout_finalize_kernel<<<NB, 256, 0, stream>>>(bsrc_s, baseB, inv_src, N);
  scale_rows_kernel<<<ceil_div(N*32,256), 256, 0, stream>>>(feats, inv_src, hs, N*32);

  const int nblk = ceil_div(N, 64);
  // layer 0: h2 = relu(inv_dst*(A@hs) @ W0 + b0) * inv_src
  agg_gemm_kernel<<<nblk, 256, 0, stream>>>(row_ptr, col, hs, W0, b0, inv_dst, inv_src, h2, N);
  // layer 1: hs = relu(inv_dst*(A@h2) @ W1 + b1) * inv_src
  agg_gemm_kernel<<<nblk, 256, 0, stream>>>(row_ptr, col, h2, W1, b1, inv_dst, inv_src, hs, N);
  // layer 2: h2 = relu(inv_dst*(A@hs) @ W2 + b2)   (no out_scale; pooled next)
  agg_gemm_kernel<<<nblk, 256, 0, stream>>>(row_ptr, col, hs, W2, b2, inv_dst, nullptr, h2, N);
  // avg pooling
  pool_kernel<<<G, 64, 0, stream>>>(h2, gid, emb, N, G);
  // MLP head
  gemm_kernel<<<dim3(ceil_div(G,64), MH/128),  256, 0, stream>>>(emb, Wm0, bm0, nullptr, nullptr, x1, G, 128, MH, 1);
  gemm_kernel<<<dim3(ceil_div(G,64), MH2/128), 256, 0, stream>>>(x1, Wm1, bm1, nullptr, nullptr, x2, G, MH, MH2, 1);
  final_dot_kernel<<<ceil_div(G*64,256), 256, 0, stream>>>(x2, Wm2, bm2, out, G);
}

// Round 6
// 814.586 us; speedup vs baseline: 1.2557x; 1.2557x over previous
//
#include <hip/hip_runtime.h>

// ---------------------------------------------------------------------------
// GNN: 3x GraphConv (norm='both') + avg-pool + MLP(128->512->256->1), fp32.
// R6: revert R5 fusion (occupancy collapse). Split csr_agg + gemm as in R4.
// csr_agg: half-wave per node, float4 per lane -> 1024B per memory instr
// (2x bytes in flight vs float2 full-wave). Counting-sort scatter packs
// (dlow,src) into one u32 and src-bucket entries into u8 (less write amp).
// ---------------------------------------------------------------------------

static inline int ceil_div(int a, int b){ return (a + b - 1) / b; }

#define B1 128          // pass-1 blocks
#define NBMAX 1024      // max buckets (N <= 131072; src ids fit in 17 bits)

// Pass 1a: per-block bucket counts for dst (job A) and src (job B).
__global__ __launch_bounds__(256) void bucket_count_kernel(
    const int* __restrict__ src, const int* __restrict__ dst,
    unsigned* __restrict__ cntA, unsigned* __restrict__ cntB,
    int E, int NB){
  __shared__ unsigned la[NBMAX], lb[NBMAX];
  int t = threadIdx.x;
  for (int i = t; i < NB; i += 256){ la[i] = 0u; lb[i] = 0u; }
  __syncthreads();
  int chunk = (E + B1 - 1) / B1;
  int e0 = blockIdx.x * chunk, e1 = min(e0 + chunk, E);
  for (int e = e0 + t; e < e1; e += 256){
    atomicAdd(&la[dst[e] >> 7], 1u);
    atomicAdd(&lb[src[e] >> 7], 1u);
  }
  __syncthreads();
  for (int i = t; i < NB; i += 256){
    cntA[(size_t)blockIdx.x * NB + i] = la[i];
    cntB[(size_t)blockIdx.x * NB + i] = lb[i];
  }
}

// Column-wise exclusive scan over blocks for each bucket; emits totals.
__global__ void scan_cols_kernel(unsigned* __restrict__ cntA, unsigned* __restrict__ cntB,
                                 unsigned* __restrict__ totals, int NB){
  int b = blockIdx.x * 256 + threadIdx.x;
  if (b >= NB) return;
  unsigned* cnt = blockIdx.y ? cntB : cntA;
  unsigned run = 0;
  for (int blk = 0; blk < B1; blk++){
    unsigned v = cnt[(size_t)blk * NB + b];
    cnt[(size_t)blk * NB + b] = run;
    run += v;
  }
  totals[(size_t)blockIdx.y * NB + b] = run;
}

// Single-block exclusive scan of bucket totals -> baseA/baseB (each NB+1).
__global__ void scan_base_kernel(const unsigned* __restrict__ totals,
                                 unsigned* __restrict__ baseA, unsigned* __restrict__ baseB,
                                 int NB, int E){
  __shared__ unsigned s[NBMAX];
  int t = threadIdx.x;  // 1024 threads, NB <= 1024
  for (int job = 0; job < 2; job++){
    unsigned* base = job ? baseB : baseA;
    unsigned x = (t < NB) ? totals[(size_t)job * NB + t] : 0u;
    s[t] = x;
    __syncthreads();
    for (int off = 1; off < NBMAX; off <<= 1){
      unsigned v = (t >= off) ? s[t - off] : 0u;
      __syncthreads();
      s[t] += v;
      __syncthreads();
    }
    if (t < NB) base[t] = s[t] - x;
    if (t == 0) base[NB] = (unsigned)E;
    __syncthreads();
  }
}

// Pass 1b: scatter edges into bucketed arrays using per-block reserved offsets.
// A-job entry: ((dst&127)<<17) | src   (one u32 instead of two ints)
// B-job entry: src&127 as u8.
__global__ __launch_bounds__(256) void bucket_scatter_kernel(
    const int* __restrict__ src, const int* __restrict__ dst,
    const unsigned* __restrict__ cntA, const unsigned* __restrict__ cntB,
    const unsigned* __restrict__ baseA, const unsigned* __restrict__ baseB,
    unsigned* __restrict__ bpack_d, unsigned char* __restrict__ bsrc_s,
    int E, int NB){
  __shared__ unsigned curA[NBMAX], curB[NBMAX];
  int t = threadIdx.x;
  for (int i = t; i < NB; i += 256){
    curA[i] = baseA[i] + cntA[(size_t)blockIdx.x * NB + i];
    curB[i] = baseB[i] + cntB[(size_t)blockIdx.x * NB + i];
  }
  __syncthreads();
  int chunk = (E + B1 - 1) / B1;
  int e0 = blockIdx.x * chunk, e1 = min(e0 + chunk, E);
  for (int e = e0 + t; e < e1; e += 256){
    int s = src[e], d = dst[e];
    unsigned p = atomicAdd(&curA[d >> 7], 1u);
    bpack_d[p] = ((unsigned)(d & 127) << 17) | (unsigned)s;
    unsigned q = atomicAdd(&curB[s >> 7], 1u);
    bsrc_s[q] = (unsigned char)(s & 127);
  }
}

// Pass 2a: per-bucket CSR finalize: row_ptr, inv_dst, col (contiguous range).
__global__ __launch_bounds__(256) void csr_finalize_kernel(
    const unsigned* __restrict__ bpack_d, const unsigned* __restrict__ baseA,
    int* __restrict__ row_ptr, float* __restrict__ inv_dst, int* __restrict__ col,
    int N, int E, int NB){
  __shared__ unsigned cnt[128];
  __shared__ unsigned scn[128];
  int b = blockIdx.x, t = threadIdx.x;
  int node0 = b << 7;
  int nn = min(128, N - node0);
  int e0 = (int)baseA[b], e1 = (int)baseA[b + 1];
  if (t < 128) cnt[t] = 0u;
  __syncthreads();
  for (int e = e0 + t; e < e1; e += 256)
    atomicAdd(&cnt[(bpack_d[e] >> 17) & 127u], 1u);
  __syncthreads();
  unsigned mycnt = (t < 128) ? cnt[t] : 0u;
  if (t < 128) scn[t] = mycnt;
  __syncthreads();
  for (int off = 1; off < 128; off <<= 1){
    unsigned v = (t < 128 && t >= off) ? scn[t - off] : 0u;
    __syncthreads();
    if (t < 128) scn[t] += v;
    __syncthreads();
  }
  if (t < nn){
    unsigned excl = scn[t] - mycnt;
    row_ptr[node0 + t] = e0 + (int)excl;
    unsigned c = mycnt < 1u ? 1u : mycnt;
    inv_dst[node0 + t] = rsqrtf((float)c);
    cnt[t] = (unsigned)e0 + excl;   // reuse as cursor
  }
  if (b == NB - 1 && t == 0) row_ptr[N] = E;
  __syncthreads();
  for (int e = e0 + t; e < e1; e += 256){
    unsigned v = bpack_d[e];
    unsigned p = atomicAdd(&cnt[(v >> 17) & 127u], 1u);
    col[p] = (int)(v & 0x1FFFFu);
  }
}

// Pass 2b: per-bucket out-degree -> inv_src.
__global__ __launch_bounds__(256) void degout_finalize_kernel(
    const unsigned char* __restrict__ bsrc_s, const unsigned* __restrict__ baseB,
    float* __restrict__ inv_src, int N){
  __shared__ unsigned cnt[128];
  int b = blockIdx.x, t = threadIdx.x;
  int node0 = b << 7;
  int nn = min(128, N - node0);
  int e0 = (int)baseB[b], e1 = (int)baseB[b + 1];
  if (t < 128) cnt[t] = 0u;
  __syncthreads();
  for (int e = e0 + t; e < e1; e += 256)
    atomicAdd(&cnt[bsrc_s[e]], 1u);
  __syncthreads();
  if (t < nn){
    unsigned c = cnt[t] < 1u ? 1u : cnt[t];
    inv_src[node0 + t] = rsqrtf((float)c);
  }
}

// hs = feats * inv_src (row scale), float4 vectorized
__global__ void scale_rows_kernel(const float* __restrict__ in, const float* __restrict__ sc,
                                  float* __restrict__ out, int n4){
  int i = blockIdx.x*blockDim.x + threadIdx.x;
  if (i < n4){
    float4 v = ((const float4*)in)[i];
    float s = sc[i >> 5];            // 32 float4 per 128-wide row
    v.x *= s; v.y *= s; v.z *= s; v.w *= s;
    ((float4*)out)[i] = v;
  }
}

// Half-wave (32 lanes) per node; lane owns a float4 (128 floats = 32 x 4).
// 1024B per wave memory instruction (2 nodes), unroll x4.
__global__ __launch_bounds__(256) void csr_agg_kernel(
    const int* __restrict__ row_ptr, const int* __restrict__ col,
    const float* __restrict__ hs, float* __restrict__ agg, int N){
  int node = (int)((blockIdx.x*256u + threadIdx.x) >> 5);
  int lane = threadIdx.x & 31;
  if (node >= N) return;
  int r0 = row_ptr[node];
  int r1 = row_ptr[node+1];
  float4 a0 = make_float4(0.f,0.f,0.f,0.f);
  float4 a1 = make_float4(0.f,0.f,0.f,0.f);
  float4 a2 = make_float4(0.f,0.f,0.f,0.f);
  float4 a3 = make_float4(0.f,0.f,0.f,0.f);
  int e = r0;
  for (; e + 3 < r1; e += 4){
    int s0 = col[e], s1 = col[e+1], s2 = col[e+2], s3 = col[e+3];
    float4 v0 = ((const float4*)(hs + (size_t)s0*128))[lane];
    float4 v1 = ((const float4*)(hs + (size_t)s1*128))[lane];
    float4 v2 = ((const float4*)(hs + (size_t)s2*128))[lane];
    float4 v3 = ((const float4*)(hs + (size_t)s3*128))[lane];
    a0.x += v0.x; a0.y += v0.y; a0.z += v0.z; a0.w += v0.w;
    a1.x += v1.x; a1.y += v1.y; a1.z += v1.z; a1.w += v1.w;
    a2.x += v2.x; a2.y += v2.y; a2.z += v2.z; a2.w += v2.w;
    a3.x += v3.x; a3.y += v3.y; a3.z += v3.z; a3.w += v3.w;
  }
  for (; e < r1; e++){
    int s0 = col[e];
    float4 v0 = ((const float4*)(hs + (size_t)s0*128))[lane];
    a0.x += v0.x; a0.y += v0.y; a0.z += v0.z; a0.w += v0.w;
  }
  float4 r;
  r.x = (a0.x + a1.x) + (a2.x + a3.x);
  r.y = (a0.y + a1.y) + (a2.y + a3.y);
  r.z = (a0.z + a1.z) + (a2.z + a3.z);
  r.w = (a0.w + a1.w) + (a2.w + a3.w);
  ((float4*)(agg + (size_t)node*128))[lane] = r;
}

// Tiled fp32 SGEMM: out[M x Ncols] = act( (A .* row_scale) @ W + bias ) .* out_scale
__global__ __launch_bounds__(256) void gemm_kernel(
    const float* __restrict__ A, const float* __restrict__ W,
    const float* __restrict__ bias, const float* __restrict__ row_scale,
    const float* __restrict__ out_scale, float* __restrict__ out,
    int M, int K, int Ncols, int do_relu){
  __shared__ float As[32][68];
  __shared__ float Bs[32][128];

  const int tid = threadIdx.x;
  const int tx = tid & 31;
  const int ty = tid >> 5;
  const int row0 = blockIdx.x * 64;
  const int col0 = blockIdx.y * 128;

  float acc[8][4];
  #pragma unroll
  for (int i = 0; i < 8; i++)
    #pragma unroll
    for (int j = 0; j < 4; j++) acc[i][j] = 0.f;

  for (int kb = 0; kb < K; kb += 32){
    #pragma unroll
    for (int i = 0; i < 2; i++){
      int flat = i*256 + tid;
      int m = flat >> 3, k4 = (flat & 7) << 2;
      int gm = row0 + m;
      float4 v = make_float4(0.f, 0.f, 0.f, 0.f);
      if (gm < M){
        v = *(const float4*)(A + (size_t)gm*K + kb + k4);
        if (row_scale){ float s = row_scale[gm]; v.x*=s; v.y*=s; v.z*=s; v.w*=s; }
      }
      As[k4+0][m] = v.x; As[k4+1][m] = v.y; As[k4+2][m] = v.z; As[k4+3][m] = v.w;
    }
    #pragma unroll
    for (int i = 0; i < 4; i++){
      int flat = i*256 + tid;
      int k = flat >> 5, j4 = (flat & 31) << 2;
      float4 v = *(const float4*)(W + (size_t)(kb + k)*Ncols + col0 + j4);
      *(float4*)&Bs[k][j4] = v;
    }
    __syncthreads();
    #pragma unroll
    for (int k = 0; k < 32; k++){
      float4 b = *(const float4*)&Bs[k][tx << 2];
      float a[8];
      #pragma unroll
      for (int i = 0; i < 8; i++) a[i] = As[k][ty*8 + i];
      #pragma unroll
      for (int i = 0; i < 8; i++){
        acc[i][0] = fmaf(a[i], b.x, acc[i][0]);
        acc[i][1] = fmaf(a[i], b.y, acc[i][1]);
        acc[i][2] = fmaf(a[i], b.z, acc[i][2]);
        acc[i][3] = fmaf(a[i], b.w, acc[i][3]);
      }
    }
    __syncthreads();
  }

  float4 bi = *(const float4*)(bias + col0 + (tx << 2));
  #pragma unroll
  for (int i = 0; i < 8; i++){
    int gm = row0 + ty*8 + i;
    if (gm < M){
      float4 v;
      v.x = acc[i][0] + bi.x; v.y = acc[i][1] + bi.y;
      v.z = acc[i][2] + bi.z; v.w = acc[i][3] + bi.w;
      if (do_relu){
        v.x = fmaxf(v.x, 0.f); v.y = fmaxf(v.y, 0.f);
        v.z = fmaxf(v.z, 0.f); v.w = fmaxf(v.w, 0.f);
      }
      if (out_scale){ float s = out_scale[gm]; v.x*=s; v.y*=s; v.z*=s; v.w*=s; }
      *(float4*)(out + (size_t)gm*Ncols + col0 + (tx << 2)) = v;
    }
  }
}

// Avg-pool per graph: graph_ids sorted -> binary search bounds, wave per graph.
__global__ void pool_kernel(const float* __restrict__ h, const int* __restrict__ gid,
                            float* __restrict__ emb, int N, int G){
  int g = blockIdx.x;
  int lane = threadIdx.x;   // 64 threads
  int lo = 0, hi = N;
  while (lo < hi){ int mid = (lo + hi) >> 1; if (gid[mid] < g) lo = mid + 1; else hi = mid; }
  int start = lo;
  hi = N;
  while (lo < hi){ int mid = (lo + hi) >> 1; if (gid[mid] <= g) lo = mid + 1; else hi = mid; }
  int end = lo;
  float ax = 0.f, ay = 0.f;
  for (int n = start; n < end; n++){
    float2 v = ((const float2*)(h + (size_t)n*128))[lane];
    ax += v.x; ay += v.y;
  }
  int c = end - start; if (c < 1) c = 1;
  float invc = 1.0f / (float)c;
  float2 r; r.x = ax * invc; r.y = ay * invc;
  ((float2*)(emb + (size_t)g*128))[lane] = r;
}

// Final 256->1: wave per graph, float4 per lane, shuffle reduce.
__global__ void final_dot_kernel(const float* __restrict__ x, const float* __restrict__ w,
                                 const float* __restrict__ b, float* __restrict__ out, int G){
  int idx = blockIdx.x*blockDim.x + threadIdx.x;
  int g = idx >> 6, lane = idx & 63;
  if (g >= G) return;
  float4 xv = ((const float4*)(x + (size_t)g*256))[lane];
  float4 wv = ((const float4*)w)[lane];
  float s = xv.x*wv.x + xv.y*wv.y + xv.z*wv.z + xv.w*wv.w;
  for (int off = 32; off > 0; off >>= 1) s += __shfl_down(s, off);
  if (lane == 0) out[g] = s + b[0];
}

extern "C" void kernel_launch(void* const* d_in, const int* in_sizes, int n_in,
                              void* d_out, int out_size, void* d_ws, size_t ws_size,
                              hipStream_t stream){
  const float* feats = (const float*)d_in[0];
  const int*   src   = (const int*)d_in[1];
  const int*   dst   = (const int*)d_in[2];
  const int*   gid   = (const int*)d_in[3];
  const float* W0 = (const float*)d_in[4];   const float* b0 = (const float*)d_in[5];
  const float* W1 = (const float*)d_in[6];   const float* b1 = (const float*)d_in[7];
  const float* W2 = (const float*)d_in[8];   const float* b2 = (const float*)d_in[9];
  const float* Wm0 = (const float*)d_in[10]; const float* bm0 = (const float*)d_in[11];
  const float* Wm1 = (const float*)d_in[12]; const float* bm1 = (const float*)d_in[13];
  const float* Wm2 = (const float*)d_in[14]; const float* bm2 = (const float*)d_in[15];
  float* out = (float*)d_out;

  const int E   = in_sizes[1];
  const int N   = in_sizes[3];
  const int G   = out_size;
  const int MH  = in_sizes[11];   // 512
  const int MH2 = in_sizes[13];   // 256
  const int NB  = ceil_div(N, 128);   // 782 for N=100000 (<= NBMAX)

  char* ws = (char*)d_ws;
  size_t off = 0;
  auto carve = [&](size_t bytes) -> char* {
    off = (off + 255) & ~(size_t)255;
    char* p = ws + off; off += bytes; return p;
  };
  float* inv_src = (float*)carve((size_t)N*4);
  float* inv_dst = (float*)carve((size_t)N*4);
  int* row_ptr = (int*)carve((size_t)(N+1)*4);
  int* col     = (int*)carve((size_t)E*4);
  float* hs  = (float*)carve((size_t)N*128*4);
  float* agg = (float*)carve((size_t)N*128*4);
  float* emb = (float*)carve((size_t)G*128*4);
  float* x1  = (float*)carve((size_t)G*MH*4);
  float* x2  = (float*)carve((size_t)G*MH2*4);

  // CSR-build temporaries alias agg (dead until first csr_agg writes it).
  // u32 layout: cntA[B1*NB] | cntB[B1*NB] | totals[2*NB] | baseA[NB+1] | baseB[NB+1]
  //             | bpack_d[E] | bsrc_s (E bytes)
  unsigned* T = (unsigned*)agg;
  unsigned* cntA   = T;
  unsigned* cntB   = cntA + (size_t)B1*NB;
  unsigned* totals = cntB + (size_t)B1*NB;
  unsigned* baseA  = totals + 2*(size_t)NB;
  unsigned* baseB  = baseA + (NB+1);
  unsigned* bpack_d = baseB + (NB+1);
  unsigned char* bsrc_s = (unsigned char*)(bpack_d + E);

  bucket_count_kernel<<<B1, 256, 0, stream>>>(src, dst, cntA, cntB, E, NB);
  scan_cols_kernel<<<dim3(ceil_div(NB,256), 2), 256, 0, stream>>>(cntA, cntB, totals, NB);
  scan_base_kernel<<<1, NBMAX, 0, stream>>>(totals, baseA, baseB, NB, E);
  bucket_scatter_kernel<<<B1, 256, 0, stream>>>(src, dst, cntA, cntB, baseA, baseB,
                                                bpack_d, bsrc_s, E, NB);
  csr_finalize_kernel<<<NB, 256, 0, stream>>>(bpack_d, baseA, row_ptr, inv_dst, col, N, E, NB);
  degout_finalize_kernel<<<NB, 256, 0, stream>>>(bsrc_s, baseB, inv_src, N);
  scale_rows_kernel<<<ceil_div(N*32,256), 256, 0, stream>>>(feats, inv_src, hs, N*32);

  const int agg_blocks = ceil_div(N*32, 256);
  dim3 ggrid(ceil_div(N,64), 1);
  // layer 0: agg = CSR-sum(hs); hs = relu(agg*inv_dst @ W0 + b0) * inv_src
  csr_agg_kernel<<<agg_blocks, 256, 0, stream>>>(row_ptr, col, hs, agg, N);
  gemm_kernel<<<ggrid, 256, 0, stream>>>(agg, W0, b0, inv_dst, inv_src, hs, N, 128, 128, 1);
  // layer 1
  csr_agg_kernel<<<agg_blocks, 256, 0, stream>>>(row_ptr, col, hs, agg, N);
  gemm_kernel<<<ggrid, 256, 0, stream>>>(agg, W1, b1, inv_dst, inv_src, hs, N, 128, 128, 1);
  // layer 2 (no out_scale: plain h3 for pooling)
  csr_agg_kernel<<<agg_blocks, 256, 0, stream>>>(row_ptr, col, hs, agg, N);
  gemm_kernel<<<ggrid, 256, 0, stream>>>(agg, W2, b2, inv_dst, nullptr, hs, N, 128, 128, 1);
  // avg pooling
  pool_kernel<<<G, 64, 0, stream>>>(hs, gid, emb, N, G);
  // MLP head
  gemm_kernel<<<dim3(ceil_div(G,64), MH/128),  256, 0, stream>>>(emb, Wm0, bm0, nullptr, nullptr, x1, G, 128, MH, 1);
  gemm_kernel<<<dim3(ceil_div(G,64), MH2/128), 256, 0, stream>>>(x1, Wm1, bm1, nullptr, nullptr, x2, G, MH, MH2, 1);
  final_dot_kernel<<<ceil_div(G*64,256), 256, 0, stream>>>(x2, Wm2, bm2, out, G);
}